// Round 2
// baseline (1109.026 us; speedup 1.0000x reference)
//
#include <hip/hip_runtime.h>
#include <math.h>

// Problem constants (match reference)
#define N_NODES   50000
#define N_EDGESC  800000
#define IN_DIM    768
#define HID       256
#define OUT_DIM   9
#define EDGE_FEAT 100
#define P_DROP    0.4f
#define INV_KEEP  (1.0f/0.6f)

// ---------------------------------------------------------------------------
// K1: gate tables. alpha = sigmoid(dot(te[t], gw[:100]) + dot(de[d], gw[100:]) + b)
// is linear over the concat -> precompute per-type and per-dist partial dots.
// tbl layout: [0,50) tdot1 | [50,178) ddot1 | [178,228) tdot2 | [228,356) ddot2
// ---------------------------------------------------------------------------
__global__ void gate_tables(const float* __restrict__ te1, const float* __restrict__ de1,
                            const float* __restrict__ g1w,
                            const float* __restrict__ te2, const float* __restrict__ de2,
                            const float* __restrict__ g2w,
                            float* __restrict__ tbl) {
    int t = threadIdx.x;
    const float* vec; const float* w;
    if (t < 50)       { vec = te1 + t*EDGE_FEAT;         w = g1w; }
    else if (t < 178) { vec = de1 + (t-50)*EDGE_FEAT;    w = g1w + EDGE_FEAT; }
    else if (t < 228) { vec = te2 + (t-178)*EDGE_FEAT;   w = g2w; }
    else if (t < 356) { vec = de2 + (t-228)*EDGE_FEAT;   w = g2w + EDGE_FEAT; }
    else return;
    float s = 0.f;
    for (int i = 0; i < EDGE_FEAT; ++i) s += vec[i]*w[i];
    tbl[t] = s;
}

// ---------------------------------------------------------------------------
// CSR build: deg histogram -> single-block scan -> bucket fill with per-edge
// gate alphas precomputed. All int work; ~30us total.
// ---------------------------------------------------------------------------
__global__ __launch_bounds__(256) void zero_deg(int* __restrict__ deg) {
    int i = blockIdx.x*256 + threadIdx.x;
    if (i < N_NODES) deg[i] = 0;
}

__global__ __launch_bounds__(256) void hist(const int* __restrict__ dst, int* __restrict__ deg) {
    int e = blockIdx.x*256 + threadIdx.x;
    if (e < N_EDGESC) atomicAdd(&deg[dst[e]], 1);
}

// one block, 1024 threads: exclusive scan of deg -> rowptr (and cursor copy)
__global__ __launch_bounds__(1024) void scan_deg(const int* __restrict__ deg,
                                                 int* __restrict__ rowptr,
                                                 int* __restrict__ cursor) {
    const int CH = 49;  // 1024*49 = 50176 >= 50000
    const int t = threadIdx.x;
    const int b = t*CH;
    const int e = min(b+CH, N_NODES);
    int s = 0;
    for (int i = b; i < e; ++i) s += deg[i];
    __shared__ int ps[1024];
    ps[t] = s;
    __syncthreads();
    // in-place Hillis-Steele inclusive scan
    for (int off = 1; off < 1024; off <<= 1) {
        int v = (t >= off) ? ps[t-off] : 0;
        __syncthreads();
        ps[t] += v;
        __syncthreads();
    }
    int run = ps[t] - s;   // exclusive prefix of this thread's chunk
    for (int i = b; i < e; ++i) {
        rowptr[i] = run;
        cursor[i] = run;
        run += deg[i];
    }
    if (t == 1023) rowptr[N_NODES] = ps[1023];
}

__global__ __launch_bounds__(256) void fill_csr(const int* __restrict__ src, const int* __restrict__ dst,
                                                const int* __restrict__ etype, const int* __restrict__ edist,
                                                const float* __restrict__ tbl,
                                                const float* __restrict__ g1b, const float* __restrict__ g2b,
                                                int* __restrict__ cursor,
                                                int* __restrict__ esrc, float* __restrict__ a1, float* __restrict__ a2) {
    int e = blockIdx.x*256 + threadIdx.x;
    if (e >= N_EDGESC) return;
    const int tt = etype[e], dd = edist[e];
    const float z1 = tbl[tt]       + tbl[50 + dd]  + g1b[0];
    const float z2 = tbl[178 + tt] + tbl[228 + dd] + g2b[0];
    const int pos = atomicAdd(&cursor[dst[e]], 1);
    esrc[pos] = src[e];
    a1[pos] = 1.f / (1.f + expf(-z1));
    a2[pos] = 1.f / (1.f + expf(-z2));
}

// ---------------------------------------------------------------------------
// K2: fused GEMM1: C[50000 x 512] = x[50000 x 768] @ [W1_msg | W1_root]
// cols 0..255 -> xt (message transform), cols 256..511 -> h (+b1, root term).
// fp32 vector GEMM, 128x128 block tile, BK=16, 256 thr, 8x8 per thread.
// ---------------------------------------------------------------------------
#define BM 128
#define BN 128
#define BK 16

__global__ __launch_bounds__(256) void gemm1(const float* __restrict__ x,
                                             const float* __restrict__ Wmsg,
                                             const float* __restrict__ Wroot,
                                             const float* __restrict__ b1,
                                             float* __restrict__ xt,
                                             float* __restrict__ h) {
    __shared__ __align__(16) float As[BK][BM];   // transposed A tile
    __shared__ __align__(16) float Bs[BK][BN];

    const int bm = blockIdx.x;
    const int bn = blockIdx.y;            // 0,1 -> msg half; 2,3 -> root half
    const int m0 = bm * BM;
    const bool is_root = (bn >= 2);
    const float* __restrict__ B = is_root ? Wroot : Wmsg;
    const int colbase = (bn & 1) * BN;

    const int t  = threadIdx.x;
    const int ty = t >> 4, tx = t & 15;
    const int ty8 = ty*8, tx8 = tx*8;

    const int ar = t >> 1;
    const int ak = (t & 1) * 8;
    const int br = t >> 4;
    const int bc = (t & 15) * 8;

    const int arow = m0 + ar;
    const float* __restrict__ aptr = x + (size_t)arow*IN_DIM + ak;
    const float* __restrict__ bptr = B + (size_t)br*HID + colbase + bc;

    float acc[8][8];
    #pragma unroll
    for (int i=0;i<8;i++)
        #pragma unroll
        for (int j=0;j<8;j++) acc[i][j]=0.f;

    float av[8]; float4 bv0, bv1;
    auto load_tile = [&](int k0) {
        if (arow < N_NODES) {
            float4 a0 = *(const float4*)(aptr + k0);
            float4 a1v = *(const float4*)(aptr + k0 + 4);
            av[0]=a0.x; av[1]=a0.y; av[2]=a0.z; av[3]=a0.w;
            av[4]=a1v.x; av[5]=a1v.y; av[6]=a1v.z; av[7]=a1v.w;
        } else {
            #pragma unroll
            for (int j=0;j<8;j++) av[j]=0.f;
        }
        bv0 = *(const float4*)(bptr + (size_t)k0*HID);
        bv1 = *(const float4*)(bptr + (size_t)k0*HID + 4);
    };

    load_tile(0);
    for (int k0 = 0; k0 < IN_DIM; k0 += BK) {
        #pragma unroll
        for (int j=0;j<8;j++) As[ak+j][ar] = av[j];
        *(float4*)&Bs[br][bc]   = bv0;
        *(float4*)&Bs[br][bc+4] = bv1;
        __syncthreads();
        if (k0 + BK < IN_DIM) load_tile(k0 + BK);
        #pragma unroll
        for (int kk=0; kk<BK; kk++) {
            float a[8], b[8];
            *(float4*)&a[0] = *(const float4*)&As[kk][ty8];
            *(float4*)&a[4] = *(const float4*)&As[kk][ty8+4];
            *(float4*)&b[0] = *(const float4*)&Bs[kk][tx8];
            *(float4*)&b[4] = *(const float4*)&Bs[kk][tx8+4];
            #pragma unroll
            for (int i=0;i<8;i++)
                #pragma unroll
                for (int j=0;j<8;j++)
                    acc[i][j] = fmaf(a[i], b[j], acc[i][j]);
        }
        __syncthreads();
    }

    float bias[8];
    #pragma unroll
    for (int j=0;j<8;j++) bias[j] = is_root ? b1[colbase + tx8 + j] : 0.f;
    float* __restrict__ dest = is_root ? h : xt;
    #pragma unroll
    for (int i=0;i<8;i++) {
        int row = m0 + ty8 + i;
        if (row >= N_NODES) break;
        float o[8];
        #pragma unroll
        for (int j=0;j<8;j++) o[j] = acc[i][j] + bias[j];
        float* dp = dest + (size_t)row*HID + colbase + tx8;
        *(float4*)dp     = *(float4*)&o[0];
        *(float4*)(dp+4) = *(float4*)&o[4];
    }
}

// ---------------------------------------------------------------------------
// K3: gather1 — one wave per dst node; lanes own float4 column slices.
// h[n] = relu((h_root[n] + sum_j a1[j]*xt[esrc[j]]) * m1[n])   (single writer)
// ---------------------------------------------------------------------------
__global__ __launch_bounds__(256) void gather1(const int* __restrict__ rowptr,
                                               const int* __restrict__ esrc, const float* __restrict__ a1,
                                               const float* __restrict__ xt,
                                               const float* __restrict__ drop1,
                                               float* __restrict__ h) {
    const int node = blockIdx.x*4 + (threadIdx.x >> 6);
    const int lane = threadIdx.x & 63;
    if (node >= N_NODES) return;
    const int beg = rowptr[node], end = rowptr[node+1];
    float4 acc = make_float4(0.f, 0.f, 0.f, 0.f);
    for (int j = beg; j < end; ++j) {
        const int s = esrc[j];          // wave-uniform
        const float a = a1[j];          // wave-uniform
        const float4 v = ((const float4*)(xt + (size_t)s*HID))[lane];
        acc.x = fmaf(a, v.x, acc.x);
        acc.y = fmaf(a, v.y, acc.y);
        acc.z = fmaf(a, v.z, acc.z);
        acc.w = fmaf(a, v.w, acc.w);
    }
    float4* hp = (float4*)(h + (size_t)node*HID);
    const float4 hv = hp[lane];
    const float4 dv = ((const float4*)(drop1 + (size_t)node*HID))[lane];
    float4 o;
    float mx = (dv.x >= P_DROP) ? INV_KEEP : 0.f;
    float my = (dv.y >= P_DROP) ? INV_KEEP : 0.f;
    float mz = (dv.z >= P_DROP) ? INV_KEEP : 0.f;
    float mw = (dv.w >= P_DROP) ? INV_KEEP : 0.f;
    o.x = fmaxf((hv.x + acc.x)*mx, 0.f);
    o.y = fmaxf((hv.y + acc.y)*my, 0.f);
    o.z = fmaxf((hv.z + acc.z)*mz, 0.f);
    o.w = fmaxf((hv.w + acc.w)*mw, 0.f);
    hp[lane] = o;
}

// ---------------------------------------------------------------------------
// K4: layer-2 GEMMs. h (already activated) -> ht2 = h@W2_msg; root2 = h@W2_root + b2.
// ---------------------------------------------------------------------------
#define R2 8
__global__ __launch_bounds__(256) void gemm2(const float* __restrict__ h,
                                             const float* __restrict__ Wm, const float* __restrict__ Wr,
                                             const float* __restrict__ b2,
                                             float* __restrict__ ht2, float* __restrict__ root2) {
    __shared__ float hs[R2][HID+1];
    __shared__ float Wms[HID][OUT_DIM];
    __shared__ float Wrs[HID][OUT_DIM];
    const int t = threadIdx.x;
    for (int i = t; i < HID*OUT_DIM; i += 256) {
        Wms[i/OUT_DIM][i%OUT_DIM] = Wm[i];
        Wrs[i/OUT_DIM][i%OUT_DIM] = Wr[i];
    }
    const int r0 = blockIdx.x * R2;
    const int lr = t >> 5;
    const int c0 = (t & 31) * 8;
    const int row = r0 + lr;
    if (row < N_NODES) {
        const float* hp = h + (size_t)row*HID + c0;
        *(float4*)&hs[lr][c0]   = *(const float4*)hp;
        *(float4*)&hs[lr][c0+4] = *(const float4*)(hp+4);
    }
    __syncthreads();
    if (t < R2*OUT_DIM) {
        const int r = t / OUT_DIM, j = t % OUT_DIM;
        const int rr = r0 + r;
        if (rr < N_NODES) {
            float sm=0.f, sr=0.f;
            #pragma unroll 8
            for (int c=0;c<HID;c++) {
                const float v = hs[r][c];
                sm = fmaf(v, Wms[c][j], sm);
                sr = fmaf(v, Wrs[c][j], sr);
            }
            ht2  [(size_t)rr*OUT_DIM + j] = sm;
            root2[(size_t)rr*OUT_DIM + j] = sr + b2[j];
        }
    }
}

// ---------------------------------------------------------------------------
// K5: gather2 — one thread per node, 9-float accumulator; fused relu-dropout.
// ht2 is 1.8MB -> L2-resident random reads.
// ---------------------------------------------------------------------------
__global__ __launch_bounds__(256) void gather2(const int* __restrict__ rowptr,
                                               const int* __restrict__ esrc, const float* __restrict__ a2,
                                               const float* __restrict__ ht2,
                                               const float* __restrict__ root2,
                                               const float* __restrict__ drop2,
                                               float* __restrict__ outp) {
    const int n = blockIdx.x*256 + threadIdx.x;
    if (n >= N_NODES) return;
    float acc[OUT_DIM];
    #pragma unroll
    for (int k=0;k<OUT_DIM;k++) acc[k] = root2[(size_t)n*OUT_DIM + k];
    const int beg = rowptr[n], end = rowptr[n+1];
    for (int j = beg; j < end; ++j) {
        const int s = esrc[j];
        const float a = a2[j];
        const float* sp = ht2 + (size_t)s*OUT_DIM;
        #pragma unroll
        for (int k=0;k<OUT_DIM;k++) acc[k] = fmaf(a, sp[k], acc[k]);
    }
    #pragma unroll
    for (int k=0;k<OUT_DIM;k++) {
        const float m = (drop2[(size_t)n*OUT_DIM + k] >= P_DROP) ? INV_KEEP : 0.f;
        const float v = acc[k]*m;
        outp[(size_t)n*OUT_DIM + k] = v > 0.f ? v : 0.f;
    }
}

// ---------------------------------------------------------------------------
extern "C" void kernel_launch(void* const* d_in, const int* in_sizes, int n_in,
                              void* d_out, int out_size, void* d_ws, size_t ws_size,
                              hipStream_t stream) {
    const float* x      = (const float*)d_in[0];
    const int*   eidx   = (const int*)d_in[1];
    const int*   etype  = (const int*)d_in[2];
    const int*   edist  = (const int*)d_in[3];
    const float* drop1  = (const float*)d_in[4];
    const float* drop2  = (const float*)d_in[5];
    const float* W1m    = (const float*)d_in[6];
    const float* W1r    = (const float*)d_in[7];
    const float* b1     = (const float*)d_in[8];
    const float* te1    = (const float*)d_in[9];
    const float* de1    = (const float*)d_in[10];
    const float* g1w    = (const float*)d_in[11];
    const float* g1b    = (const float*)d_in[12];
    const float* W2m    = (const float*)d_in[13];
    const float* W2r    = (const float*)d_in[14];
    const float* b2     = (const float*)d_in[15];
    const float* te2    = (const float*)d_in[16];
    const float* de2    = (const float*)d_in[17];
    const float* g2w    = (const float*)d_in[18];
    const float* g2b    = (const float*)d_in[19];
    float* out = (float*)d_out;

    const int* src = eidx;
    const int* dst = eidx + N_EDGESC;

    // workspace layout (4-byte elements; all offsets multiples of 4 elems -> 16B aligned)
    float* ws    = (float*)d_ws;
    float* xt    = ws;                                   // 12,800,000
    float* h     = xt    + (size_t)N_NODES*HID;          // 12,800,000
    float* ht2   = h     + (size_t)N_NODES*HID;          // 450,000
    float* root2 = ht2   + (size_t)N_NODES*OUT_DIM;      // 450,000
    float* tbl   = root2 + (size_t)N_NODES*OUT_DIM;      // 356 (pad to 384)
    float* a1    = tbl   + 384;                          // 800,000
    float* a2    = a1    + N_EDGESC;                     // 800,000
    int*   esrc  = (int*)(a2 + N_EDGESC);                // 800,000
    int*   deg   = esrc  + N_EDGESC;                     // 50,000
    int*   rowptr= deg   + N_NODES;                      // 50,001
    int*   cursor= rowptr+ (N_NODES+1);                  // 50,000

    gate_tables<<<1, 512, 0, stream>>>(te1, de1, g1w, te2, de2, g2w, tbl);
    zero_deg<<<(N_NODES+255)/256, 256, 0, stream>>>(deg);
    hist<<<(N_EDGESC+255)/256, 256, 0, stream>>>(dst, deg);
    scan_deg<<<1, 1024, 0, stream>>>(deg, rowptr, cursor);
    fill_csr<<<(N_EDGESC+255)/256, 256, 0, stream>>>(src, dst, etype, edist, tbl, g1b, g2b,
                                                     cursor, esrc, a1, a2);
    gemm1<<<dim3((N_NODES+BM-1)/BM, 4), 256, 0, stream>>>(x, W1m, W1r, b1, xt, h);
    gather1<<<(N_NODES+3)/4, 256, 0, stream>>>(rowptr, esrc, a1, xt, drop1, h);
    gemm2<<<(N_NODES+R2-1)/R2, 256, 0, stream>>>(h, W2m, W2r, b2, ht2, root2);
    gather2<<<(N_NODES+255)/256, 256, 0, stream>>>(rowptr, esrc, a2, ht2, root2, drop2, out);
}

// Round 3
// 838.159 us; speedup vs baseline: 1.3232x; 1.3232x over previous
//
#include <hip/hip_runtime.h>
#include <math.h>

// Problem constants (match reference)
#define N_NODES   50000
#define N_EDGESC  800000
#define IN_DIM    768
#define HID       256
#define OUT_DIM   9
#define EDGE_FEAT 100
#define P_DROP    0.4f
#define INV_KEEP  (1.0f/0.6f)

typedef __attribute__((ext_vector_type(8))) short bf16x8;
typedef __attribute__((ext_vector_type(4))) float f32x4;

__device__ __forceinline__ ushort f2bf(float f) {
    uint u = __float_as_uint(f);
    uint r = (u + 0x7fffu + ((u >> 16) & 1u)) >> 16;   // RNE
    return (ushort)r;
}
__device__ __forceinline__ float bf2f(ushort h) {
    return __uint_as_float(((uint)h) << 16);
}

// ---------------------------------------------------------------------------
// K1: gate tables. alpha = sigmoid(dot(te[t], gw[:100]) + dot(de[d], gw[100:]) + b)
// tbl layout: [0,50) tdot1 | [50,178) ddot1 | [178,228) tdot2 | [228,356) ddot2
// ---------------------------------------------------------------------------
__global__ void gate_tables(const float* __restrict__ te1, const float* __restrict__ de1,
                            const float* __restrict__ g1w,
                            const float* __restrict__ te2, const float* __restrict__ de2,
                            const float* __restrict__ g2w,
                            float* __restrict__ tbl) {
    int t = threadIdx.x;
    const float* vec; const float* w;
    if (t < 50)       { vec = te1 + t*EDGE_FEAT;         w = g1w; }
    else if (t < 178) { vec = de1 + (t-50)*EDGE_FEAT;    w = g1w + EDGE_FEAT; }
    else if (t < 228) { vec = te2 + (t-178)*EDGE_FEAT;   w = g2w; }
    else if (t < 356) { vec = de2 + (t-228)*EDGE_FEAT;   w = g2w + EDGE_FEAT; }
    else return;
    float s = 0.f;
    for (int i = 0; i < EDGE_FEAT; ++i) s += vec[i]*w[i];
    tbl[t] = s;
}

// ---------------------------------------------------------------------------
// B' prep: BT[n][k] bf16 hi/lo planes, n in [0,512) = [Wmsg cols | Wroot cols],
// k in [0,768). W stored [k][256] row-major.
// ---------------------------------------------------------------------------
__global__ __launch_bounds__(256) void bt_prep(const float* __restrict__ Wm, const float* __restrict__ Wr,
                                               ushort* __restrict__ BTh, ushort* __restrict__ BTl) {
    int tid = blockIdx.x*256 + threadIdx.x;
    if (tid >= 512*IN_DIM) return;
    int n = tid / IN_DIM, k = tid % IN_DIM;
    float w = (n < HID) ? Wm[(size_t)k*HID + n] : Wr[(size_t)k*HID + (n - HID)];
    ushort hi = f2bf(w);
    BTh[tid] = hi;
    BTl[tid] = f2bf(w - bf2f(hi));
}

// ---------------------------------------------------------------------------
// CSR build: deg histogram -> single-block scan -> bucket fill with per-edge
// gate alphas precomputed.
// ---------------------------------------------------------------------------
__global__ __launch_bounds__(256) void zero_deg(int* __restrict__ deg) {
    int i = blockIdx.x*256 + threadIdx.x;
    if (i < N_NODES) deg[i] = 0;
}

__global__ __launch_bounds__(256) void hist(const int* __restrict__ dst, int* __restrict__ deg) {
    int e = blockIdx.x*256 + threadIdx.x;
    if (e < N_EDGESC) atomicAdd(&deg[dst[e]], 1);
}

__global__ __launch_bounds__(1024) void scan_deg(const int* __restrict__ deg,
                                                 int* __restrict__ rowptr,
                                                 int* __restrict__ cursor) {
    const int CH = 49;  // 1024*49 = 50176 >= 50000
    const int t = threadIdx.x;
    const int b = t*CH;
    const int e = min(b+CH, N_NODES);
    int s = 0;
    for (int i = b; i < e; ++i) s += deg[i];
    __shared__ int ps[1024];
    ps[t] = s;
    __syncthreads();
    for (int off = 1; off < 1024; off <<= 1) {
        int v = (t >= off) ? ps[t-off] : 0;
        __syncthreads();
        ps[t] += v;
        __syncthreads();
    }
    int run = ps[t] - s;
    for (int i = b; i < e; ++i) {
        rowptr[i] = run;
        cursor[i] = run;
        run += deg[i];
    }
    if (t == 1023) rowptr[N_NODES] = ps[1023];
}

__global__ __launch_bounds__(256) void fill_csr(const int* __restrict__ src, const int* __restrict__ dst,
                                                const int* __restrict__ etype, const int* __restrict__ edist,
                                                const float* __restrict__ tbl,
                                                const float* __restrict__ g1b, const float* __restrict__ g2b,
                                                int* __restrict__ cursor,
                                                int* __restrict__ esrc, float* __restrict__ a1, float* __restrict__ a2) {
    int e = blockIdx.x*256 + threadIdx.x;
    if (e >= N_EDGESC) return;
    const int tt = etype[e], dd = edist[e];
    const float z1 = tbl[tt]       + tbl[50 + dd]  + g1b[0];
    const float z2 = tbl[178 + tt] + tbl[228 + dd] + g2b[0];
    const int pos = atomicAdd(&cursor[dst[e]], 1);
    esrc[pos] = src[e];
    a1[pos] = 1.f / (1.f + expf(-z1));
    a2[pos] = 1.f / (1.f + expf(-z2));
}

// ---------------------------------------------------------------------------
// K2: split-bf16 MFMA GEMM1: C[50000 x 512] = x[50000 x 768] @ [W1_msg | W1_root]
// x split on the fly into hi/lo bf16 planes during LDS staging; B planes
// pre-split by bt_prep. acc += Ah*Bh + Ah*Bl + Al*Bh (f32 accumulate).
// 128x128 tile, BK=32, 4 waves (2x2), each wave 64x64 = 4x4 frags 16x16x32.
// ---------------------------------------------------------------------------
#define LDK 40   // 32 + 8 pad (ushort) -> row stride 80B, bank-quad stride 20

__global__ __launch_bounds__(256) void gemm1_mfma(const float* __restrict__ x,
                                                  const ushort* __restrict__ BTh,
                                                  const ushort* __restrict__ BTl,
                                                  const float* __restrict__ b1,
                                                  float* __restrict__ xt,
                                                  float* __restrict__ h) {
    __shared__ __align__(16) ushort Ah[128][LDK];
    __shared__ __align__(16) ushort Al[128][LDK];
    __shared__ __align__(16) ushort Bh[128][LDK];
    __shared__ __align__(16) ushort Bl[128][LDK];

    const int t    = threadIdx.x;
    const int wave = t >> 6, lane = t & 63;
    const int wm   = wave >> 1, wn = wave & 1;
    const int m0   = blockIdx.x * 128;
    const int nb   = blockIdx.y;         // 0..3 ; col base nb*128 in 512-wide C
    const int n0   = nb * 128;

    // staging maps
    const int sr = t >> 1;               // A/B row 0..127
    const int sk = (t & 1) * 16;         // col offset 0 or 16
    const int arow   = m0 + sr;
    const bool avalid = arow < N_NODES;
    const float*  ap  = x   + (size_t)(avalid ? arow : 0) * IN_DIM + sk;
    const ushort* bph = BTh + (size_t)(n0 + sr) * IN_DIM + sk;
    const ushort* bpl = BTl + (size_t)(n0 + sr) * IN_DIM + sk;

    // fragment lane decomposition
    const int fr = lane & 15;            // row (A) / col (B) within fragment
    const int kg = lane >> 4;            // k-group; k offset = kg*8

    f32x4 acc[4][4];
    #pragma unroll
    for (int i=0;i<4;i++)
        #pragma unroll
        for (int j=0;j<4;j++) acc[i][j] = (f32x4){0.f,0.f,0.f,0.f};

    float av[16];
    uint4 bhv0, bhv1, blv0, blv1;
    auto stage_load = [&](int kb) {
        if (avalid) {
            const float4* p = (const float4*)(ap + kb);
            float4 v0 = p[0], v1 = p[1], v2 = p[2], v3 = p[3];
            av[0]=v0.x; av[1]=v0.y; av[2]=v0.z; av[3]=v0.w;
            av[4]=v1.x; av[5]=v1.y; av[6]=v1.z; av[7]=v1.w;
            av[8]=v2.x; av[9]=v2.y; av[10]=v2.z; av[11]=v2.w;
            av[12]=v3.x; av[13]=v3.y; av[14]=v3.z; av[15]=v3.w;
        } else {
            #pragma unroll
            for (int j=0;j<16;j++) av[j]=0.f;
        }
        const uint4* ph = (const uint4*)(bph + kb);
        const uint4* pl = (const uint4*)(bpl + kb);
        bhv0 = ph[0]; bhv1 = ph[1];
        blv0 = pl[0]; blv1 = pl[1];
    };

    stage_load(0);
    for (int kb = 0; kb < IN_DIM; kb += 32) {
        __syncthreads();   // previous iteration's ds_reads complete
        // convert + commit A
        uint hp[8], lp[8];
        #pragma unroll
        for (int jj=0;jj<8;jj++) {
            float v0 = av[2*jj], v1 = av[2*jj+1];
            ushort h0 = f2bf(v0), h1 = f2bf(v1);
            ushort l0 = f2bf(v0 - bf2f(h0)), l1 = f2bf(v1 - bf2f(h1));
            hp[jj] = (uint)h0 | ((uint)h1 << 16);
            lp[jj] = (uint)l0 | ((uint)l1 << 16);
        }
        *(uint4*)&Ah[sr][sk]   = *(uint4*)&hp[0];
        *(uint4*)&Ah[sr][sk+8] = *(uint4*)&hp[4];
        *(uint4*)&Al[sr][sk]   = *(uint4*)&lp[0];
        *(uint4*)&Al[sr][sk+8] = *(uint4*)&lp[4];
        *(uint4*)&Bh[sr][sk]   = bhv0;
        *(uint4*)&Bh[sr][sk+8] = bhv1;
        *(uint4*)&Bl[sr][sk]   = blv0;
        *(uint4*)&Bl[sr][sk+8] = blv1;
        __syncthreads();
        if (kb + 32 < IN_DIM) stage_load(kb + 32);   // overlap with MFMAs below

        bf16x8 afh[4], afl[4], bfh[4], bfl[4];
        #pragma unroll
        for (int i=0;i<4;i++) {
            const int r = wm*64 + i*16 + fr;
            afh[i] = *(const bf16x8*)&Ah[r][kg*8];
            afl[i] = *(const bf16x8*)&Al[r][kg*8];
        }
        #pragma unroll
        for (int j=0;j<4;j++) {
            const int c = wn*64 + j*16 + fr;
            bfh[j] = *(const bf16x8*)&Bh[c][kg*8];
            bfl[j] = *(const bf16x8*)&Bl[c][kg*8];
        }
        #pragma unroll
        for (int i=0;i<4;i++)
            #pragma unroll
            for (int j=0;j<4;j++) {
                acc[i][j] = __builtin_amdgcn_mfma_f32_16x16x32_bf16(afh[i], bfh[j], acc[i][j], 0, 0, 0);
                acc[i][j] = __builtin_amdgcn_mfma_f32_16x16x32_bf16(afh[i], bfl[j], acc[i][j], 0, 0, 0);
                acc[i][j] = __builtin_amdgcn_mfma_f32_16x16x32_bf16(afl[i], bfh[j], acc[i][j], 0, 0, 0);
            }
    }

    // epilogue: C/D map col=lane&15, row=(lane>>4)*4+reg  [m89/m91]
    const bool is_root = (nb >= 2);
    float* __restrict__ dest = is_root ? h : xt;
    const int cb = is_root ? (n0 - 256) : n0;
    #pragma unroll
    for (int j=0;j<4;j++) {
        const int col  = cb + wn*64 + j*16 + fr;
        const float bias = is_root ? b1[col] : 0.f;
        #pragma unroll
        for (int i=0;i<4;i++) {
            const int rbase = m0 + wm*64 + i*16 + kg*4;
            #pragma unroll
            for (int r=0;r<4;r++) {
                const int row = rbase + r;
                if (row < N_NODES) dest[(size_t)row*HID + col] = acc[i][j][r] + bias;
            }
        }
    }
}

// ---------------------------------------------------------------------------
// K3: gather1 — one wave per dst node; lanes own float4 column slices.
// h[n] = relu((h_root[n] + sum_j a1[j]*xt[esrc[j]]) * m1[n])   (single writer)
// ---------------------------------------------------------------------------
__global__ __launch_bounds__(256) void gather1(const int* __restrict__ rowptr,
                                               const int* __restrict__ esrc, const float* __restrict__ a1,
                                               const float* __restrict__ xt,
                                               const float* __restrict__ drop1,
                                               float* __restrict__ h) {
    const int node = blockIdx.x*4 + (threadIdx.x >> 6);
    const int lane = threadIdx.x & 63;
    if (node >= N_NODES) return;
    const int beg = rowptr[node], end = rowptr[node+1];
    float4 acc = make_float4(0.f, 0.f, 0.f, 0.f);
    for (int j = beg; j < end; ++j) {
        const int s = esrc[j];
        const float a = a1[j];
        const float4 v = ((const float4*)(xt + (size_t)s*HID))[lane];
        acc.x = fmaf(a, v.x, acc.x);
        acc.y = fmaf(a, v.y, acc.y);
        acc.z = fmaf(a, v.z, acc.z);
        acc.w = fmaf(a, v.w, acc.w);
    }
    float4* hp = (float4*)(h + (size_t)node*HID);
    const float4 hv = hp[lane];
    const float4 dv = ((const float4*)(drop1 + (size_t)node*HID))[lane];
    float4 o;
    float mx = (dv.x >= P_DROP) ? INV_KEEP : 0.f;
    float my = (dv.y >= P_DROP) ? INV_KEEP : 0.f;
    float mz = (dv.z >= P_DROP) ? INV_KEEP : 0.f;
    float mw = (dv.w >= P_DROP) ? INV_KEEP : 0.f;
    o.x = fmaxf((hv.x + acc.x)*mx, 0.f);
    o.y = fmaxf((hv.y + acc.y)*my, 0.f);
    o.z = fmaxf((hv.z + acc.z)*mz, 0.f);
    o.w = fmaxf((hv.w + acc.w)*mw, 0.f);
    hp[lane] = o;
}

// ---------------------------------------------------------------------------
// K4: layer-2 GEMMs. h (activated) -> ht2 = h@W2_msg; root2 = h@W2_root + b2.
// ---------------------------------------------------------------------------
#define R2 8
__global__ __launch_bounds__(256) void gemm2(const float* __restrict__ h,
                                             const float* __restrict__ Wm, const float* __restrict__ Wr,
                                             const float* __restrict__ b2,
                                             float* __restrict__ ht2, float* __restrict__ root2) {
    __shared__ float hs[R2][HID+1];
    __shared__ float Wms[HID][OUT_DIM];
    __shared__ float Wrs[HID][OUT_DIM];
    const int t = threadIdx.x;
    for (int i = t; i < HID*OUT_DIM; i += 256) {
        Wms[i/OUT_DIM][i%OUT_DIM] = Wm[i];
        Wrs[i/OUT_DIM][i%OUT_DIM] = Wr[i];
    }
    const int r0 = blockIdx.x * R2;
    const int lr = t >> 5;
    const int c0 = (t & 31) * 8;
    const int row = r0 + lr;
    if (row < N_NODES) {
        const float* hp = h + (size_t)row*HID + c0;
        *(float4*)&hs[lr][c0]   = *(const float4*)hp;
        *(float4*)&hs[lr][c0+4] = *(const float4*)(hp+4);
    }
    __syncthreads();
    if (t < R2*OUT_DIM) {
        const int r = t / OUT_DIM, j = t % OUT_DIM;
        const int rr = r0 + r;
        if (rr < N_NODES) {
            float sm=0.f, sr=0.f;
            #pragma unroll 8
            for (int c=0;c<HID;c++) {
                const float v = hs[r][c];
                sm = fmaf(v, Wms[c][j], sm);
                sr = fmaf(v, Wrs[c][j], sr);
            }
            ht2  [(size_t)rr*OUT_DIM + j] = sm;
            root2[(size_t)rr*OUT_DIM + j] = sr + b2[j];
        }
    }
}

// ---------------------------------------------------------------------------
// K5: gather2 — one thread per node, 9-float accumulator; fused relu-dropout.
// ---------------------------------------------------------------------------
__global__ __launch_bounds__(256) void gather2(const int* __restrict__ rowptr,
                                               const int* __restrict__ esrc, const float* __restrict__ a2,
                                               const float* __restrict__ ht2,
                                               const float* __restrict__ root2,
                                               const float* __restrict__ drop2,
                                               float* __restrict__ outp) {
    const int n = blockIdx.x*256 + threadIdx.x;
    if (n >= N_NODES) return;
    float acc[OUT_DIM];
    #pragma unroll
    for (int k=0;k<OUT_DIM;k++) acc[k] = root2[(size_t)n*OUT_DIM + k];
    const int beg = rowptr[n], end = rowptr[n+1];
    for (int j = beg; j < end; ++j) {
        const int s = esrc[j];
        const float a = a2[j];
        const float* sp = ht2 + (size_t)s*OUT_DIM;
        #pragma unroll
        for (int k=0;k<OUT_DIM;k++) acc[k] = fmaf(a, sp[k], acc[k]);
    }
    #pragma unroll
    for (int k=0;k<OUT_DIM;k++) {
        const float m = (drop2[(size_t)n*OUT_DIM + k] >= P_DROP) ? INV_KEEP : 0.f;
        const float v = acc[k]*m;
        outp[(size_t)n*OUT_DIM + k] = v > 0.f ? v : 0.f;
    }
}

// ---------------------------------------------------------------------------
extern "C" void kernel_launch(void* const* d_in, const int* in_sizes, int n_in,
                              void* d_out, int out_size, void* d_ws, size_t ws_size,
                              hipStream_t stream) {
    const float* x      = (const float*)d_in[0];
    const int*   eidx   = (const int*)d_in[1];
    const int*   etype  = (const int*)d_in[2];
    const int*   edist  = (const int*)d_in[3];
    const float* drop1  = (const float*)d_in[4];
    const float* drop2  = (const float*)d_in[5];
    const float* W1m    = (const float*)d_in[6];
    const float* W1r    = (const float*)d_in[7];
    const float* b1     = (const float*)d_in[8];
    const float* te1    = (const float*)d_in[9];
    const float* de1    = (const float*)d_in[10];
    const float* g1w    = (const float*)d_in[11];
    const float* g1b    = (const float*)d_in[12];
    const float* W2m    = (const float*)d_in[13];
    const float* W2r    = (const float*)d_in[14];
    const float* b2     = (const float*)d_in[15];
    const float* te2    = (const float*)d_in[16];
    const float* de2    = (const float*)d_in[17];
    const float* g2w    = (const float*)d_in[18];
    const float* g2b    = (const float*)d_in[19];
    float* out = (float*)d_out;

    const int* src = eidx;
    const int* dst = eidx + N_EDGESC;

    // workspace layout (4-byte elements; offsets 16B aligned)
    float* ws    = (float*)d_ws;
    float* xt    = ws;                                   // 12,800,000
    float* h     = xt    + (size_t)N_NODES*HID;          // 12,800,000
    float* ht2   = h     + (size_t)N_NODES*HID;          // 450,000
    float* root2 = ht2   + (size_t)N_NODES*OUT_DIM;      // 450,000
    float* tbl   = root2 + (size_t)N_NODES*OUT_DIM;      // 356 (pad to 384)
    float* a1    = tbl   + 384;                          // 800,000
    float* a2    = a1    + N_EDGESC;                     // 800,000
    int*   esrc  = (int*)(a2 + N_EDGESC);                // 800,000
    int*   deg   = esrc  + N_EDGESC;                     // 50,000
    int*   rowptr= deg   + N_NODES;                      // 50,001
    int*   cursor= rowptr+ (N_NODES+1);                  // 50,000 (pad to 50,004)
    ushort* BTh  = (ushort*)(cursor + 50004);            // 512*768 ushort
    ushort* BTl  = BTh + (size_t)512*IN_DIM;             // 512*768 ushort

    gate_tables<<<1, 512, 0, stream>>>(te1, de1, g1w, te2, de2, g2w, tbl);
    bt_prep<<<(512*IN_DIM+255)/256, 256, 0, stream>>>(W1m, W1r, BTh, BTl);
    zero_deg<<<(N_NODES+255)/256, 256, 0, stream>>>(deg);
    hist<<<(N_EDGESC+255)/256, 256, 0, stream>>>(dst, deg);
    scan_deg<<<1, 1024, 0, stream>>>(deg, rowptr, cursor);
    fill_csr<<<(N_EDGESC+255)/256, 256, 0, stream>>>(src, dst, etype, edist, tbl, g1b, g2b,
                                                     cursor, esrc, a1, a2);
    gemm1_mfma<<<dim3((N_NODES+127)/128, 4), 256, 0, stream>>>(x, BTh, BTl, b1, xt, h);
    gather1<<<(N_NODES+3)/4, 256, 0, stream>>>(rowptr, esrc, a1, xt, drop1, h);
    gemm2<<<(N_NODES+R2-1)/R2, 256, 0, stream>>>(h, W2m, W2r, b2, ht2, root2);
    gather2<<<(N_NODES+255)/256, 256, 0, stream>>>(rowptr, esrc, a2, ht2, root2, drop2, out);
}

// Round 5
// 656.190 us; speedup vs baseline: 1.6901x; 1.2773x over previous
//
#include <hip/hip_runtime.h>
#include <math.h>

// Problem constants (match reference)
#define N_NODES   50000
#define N_EDGESC  800000
#define IN_DIM    768
#define HID       256
#define OUT_DIM   9
#define EDGE_FEAT 100
#define P_DROP    0.4f
#define INV_KEEP  (1.0f/0.6f)

typedef __attribute__((ext_vector_type(8))) short bf16x8;
typedef __attribute__((ext_vector_type(4))) float f32x4;

__device__ __forceinline__ ushort f2bf(float f) {
    uint u = __float_as_uint(f);
    uint r = (u + 0x7fffu + ((u >> 16) & 1u)) >> 16;   // RNE
    return (ushort)r;
}
__device__ __forceinline__ float bf2f(ushort h) {
    return __uint_as_float(((uint)h) << 16);
}

// LDS swizzles: XOR row bits into byte bits 4..6 (keeps 16B blocks intact).
// 64B rows (gemm1 tiles): 2-way max on reads/writes.
__device__ __forceinline__ int swz1(int row, int byte) { return byte ^ (((row >> 1) & 3) << 4); }
// 512B rows (gemm2 tiles): full 8-quad spread.
__device__ __forceinline__ int swz2(int row, int byte) { return byte ^ ((row & 7) << 4); }

// ---------------------------------------------------------------------------
// K1: gate tables. alpha = sigmoid(dot(te[t], gw[:100]) + dot(de[d], gw[100:]) + b)
// tbl layout: [0,50) tdot1 | [50,178) ddot1 | [178,228) tdot2 | [228,356) ddot2
// ---------------------------------------------------------------------------
__global__ void gate_tables(const float* __restrict__ te1, const float* __restrict__ de1,
                            const float* __restrict__ g1w,
                            const float* __restrict__ te2, const float* __restrict__ de2,
                            const float* __restrict__ g2w,
                            float* __restrict__ tbl) {
    int t = threadIdx.x;
    const float* vec; const float* w;
    if (t < 50)       { vec = te1 + t*EDGE_FEAT;         w = g1w; }
    else if (t < 178) { vec = de1 + (t-50)*EDGE_FEAT;    w = g1w + EDGE_FEAT; }
    else if (t < 228) { vec = te2 + (t-178)*EDGE_FEAT;   w = g2w; }
    else if (t < 356) { vec = de2 + (t-228)*EDGE_FEAT;   w = g2w + EDGE_FEAT; }
    else return;
    float s = 0.f;
    for (int i = 0; i < EDGE_FEAT; ++i) s += vec[i]*w[i];
    tbl[t] = s;
}

// ---------------------------------------------------------------------------
// B' prep for gemm1: BT[n][k] bf16 hi/lo planes, n in [0,512) = [Wmsg | Wroot]
// ---------------------------------------------------------------------------
__global__ __launch_bounds__(256) void bt_prep(const float* __restrict__ Wm, const float* __restrict__ Wr,
                                               ushort* __restrict__ BTh, ushort* __restrict__ BTl) {
    int tid = blockIdx.x*256 + threadIdx.x;
    if (tid >= 512*IN_DIM) return;
    int n = tid / IN_DIM, k = tid % IN_DIM;
    float w = (n < HID) ? Wm[(size_t)k*HID + n] : Wr[(size_t)k*HID + (n - HID)];
    ushort hi = f2bf(w);
    BTh[tid] = hi;
    BTl[tid] = f2bf(w - bf2f(hi));
}

// ---------------------------------------------------------------------------
// W2 pack for gemm2 MFMA: WPT[32][256] bf16 = B^T layout.
// cols 0..8 = W2_msg, cols 16..24 = W2_root, rest zero.
// ---------------------------------------------------------------------------
__global__ __launch_bounds__(256) void w2_pack(const float* __restrict__ Wm, const float* __restrict__ Wr,
                                               ushort* __restrict__ WPT) {
    int i = blockIdx.x*256 + threadIdx.x;
    if (i >= 32*256) return;
    int col = i >> 8, k = i & 255;
    float v = 0.f;
    if (col < 9)                    v = Wm[(size_t)k*OUT_DIM + col];
    else if (col >= 16 && col < 25) v = Wr[(size_t)k*OUT_DIM + (col - 16)];
    WPT[i] = f2bf(v);
}

// ---------------------------------------------------------------------------
// CSR build: histogram -> 3-pass multi-block scan -> bucket fill.
// ---------------------------------------------------------------------------
__global__ __launch_bounds__(256) void zero_deg(int* __restrict__ deg) {
    int i = blockIdx.x*256 + threadIdx.x;
    if (i < N_NODES) deg[i] = 0;
}

__global__ __launch_bounds__(256) void hist(const int* __restrict__ dst, int* __restrict__ deg) {
    int e = blockIdx.x*256 + threadIdx.x;
    if (e < N_EDGESC) atomicAdd(&deg[dst[e]], 1);
}

__global__ __launch_bounds__(256) void scan_p1(const int* __restrict__ deg, int* __restrict__ bsum) {
    __shared__ int sd[256];
    int i = blockIdx.x*256 + threadIdx.x;
    sd[threadIdx.x] = (i < N_NODES) ? deg[i] : 0;
    __syncthreads();
    for (int off = 128; off; off >>= 1) {
        if (threadIdx.x < off) sd[threadIdx.x] += sd[threadIdx.x + off];
        __syncthreads();
    }
    if (!threadIdx.x) bsum[blockIdx.x] = sd[0];
}

__global__ __launch_bounds__(256) void scan_p2(const int* __restrict__ bsum, int* __restrict__ boff) {
    __shared__ int ps[256];
    const int t = threadIdx.x;
    const int NB = 196;
    int v = (t < NB) ? bsum[t] : 0;
    ps[t] = v;
    __syncthreads();
    for (int off = 1; off < 256; off <<= 1) {
        int u = (t >= off) ? ps[t-off] : 0;
        __syncthreads();
        ps[t] += u;
        __syncthreads();
    }
    if (t < NB) boff[t] = ps[t] - v;
}

__global__ __launch_bounds__(256) void scan_p3(const int* __restrict__ deg, const int* __restrict__ boff,
                                               int* __restrict__ rowptr, int* __restrict__ cursor) {
    __shared__ int ps[256];
    const int t = threadIdx.x;
    const int i = blockIdx.x*256 + t;
    int v = (i < N_NODES) ? deg[i] : 0;
    ps[t] = v;
    __syncthreads();
    for (int off = 1; off < 256; off <<= 1) {
        int u = (t >= off) ? ps[t-off] : 0;
        __syncthreads();
        ps[t] += u;
        __syncthreads();
    }
    if (i < N_NODES) {
        int ex = boff[blockIdx.x] + ps[t] - v;
        rowptr[i] = ex;
        cursor[i] = ex;
        if (i == N_NODES-1) rowptr[N_NODES] = ex + v;
    }
}

__global__ __launch_bounds__(256) void fill_csr(const int* __restrict__ src, const int* __restrict__ dst,
                                                const int* __restrict__ etype, const int* __restrict__ edist,
                                                const float* __restrict__ tbl,
                                                const float* __restrict__ g1b, const float* __restrict__ g2b,
                                                int* __restrict__ cursor,
                                                int* __restrict__ esrc, float* __restrict__ a1, float* __restrict__ a2) {
    int e = blockIdx.x*256 + threadIdx.x;
    if (e >= N_EDGESC) return;
    const int tt = etype[e], dd = edist[e];
    const float z1 = tbl[tt]       + tbl[50 + dd]  + g1b[0];
    const float z2 = tbl[178 + tt] + tbl[228 + dd] + g2b[0];
    const int pos = atomicAdd(&cursor[dst[e]], 1);
    esrc[pos] = src[e];
    a1[pos] = 1.f / (1.f + expf(-z1));
    a2[pos] = 1.f / (1.f + expf(-z2));
}

// ---------------------------------------------------------------------------
// K2: split-bf16 MFMA GEMM1: C[50000 x 512] = x @ [W1_msg | W1_root]
// 32KB swizzled LDS (no pad) -> 5 blocks/CU for cross-block barrier overlap.
// msg half -> xtb (bf16), root half -> h (f32, +b1).
// ---------------------------------------------------------------------------
__global__ __launch_bounds__(256) void gemm1_mfma(const float* __restrict__ x,
                                                  const ushort* __restrict__ BTh,
                                                  const ushort* __restrict__ BTl,
                                                  const float* __restrict__ b1,
                                                  ushort* __restrict__ xtb,
                                                  float* __restrict__ h) {
    __shared__ __align__(16) ushort Ah[128*32];   // 8KB each, 64B rows, swizzled
    __shared__ __align__(16) ushort Al[128*32];
    __shared__ __align__(16) ushort Bh[128*32];
    __shared__ __align__(16) ushort Bl[128*32];

    const int t    = threadIdx.x;
    const int wave = t >> 6, lane = t & 63;
    const int wm   = wave >> 1, wn = wave & 1;
    const int nb   = blockIdx.x;         // 0..3 column block (x-fastest: A-tile sharers adjacent)
    const int m0   = blockIdx.y * 128;
    const int n0   = nb * 128;

    // staging maps: 2 threads/row, 16 elems (32B) each
    const int sr = t >> 1;
    const int sk = (t & 1) * 16;
    const int arow   = m0 + sr;
    const bool avalid = arow < N_NODES;
    const float*  ap  = x   + (size_t)(avalid ? arow : 0) * IN_DIM + sk;
    const ushort* bph = BTh + (size_t)(n0 + sr) * IN_DIM + sk;
    const ushort* bpl = BTl + (size_t)(n0 + sr) * IN_DIM + sk;

    const int fr = lane & 15;
    const int kg = lane >> 4;

    f32x4 acc[4][4];
    #pragma unroll
    for (int i=0;i<4;i++)
        #pragma unroll
        for (int j=0;j<4;j++) acc[i][j] = (f32x4){0.f,0.f,0.f,0.f};

    float av[16];
    uint4 bhv0, bhv1, blv0, blv1;
    auto stage_load = [&](int kb) {
        if (avalid) {
            const float4* p = (const float4*)(ap + kb);
            float4 v0 = p[0], v1 = p[1], v2 = p[2], v3 = p[3];
            av[0]=v0.x; av[1]=v0.y; av[2]=v0.z; av[3]=v0.w;
            av[4]=v1.x; av[5]=v1.y; av[6]=v1.z; av[7]=v1.w;
            av[8]=v2.x; av[9]=v2.y; av[10]=v2.z; av[11]=v2.w;
            av[12]=v3.x; av[13]=v3.y; av[14]=v3.z; av[15]=v3.w;
        } else {
            #pragma unroll
            for (int j=0;j<16;j++) av[j]=0.f;
        }
        const uint4* ph = (const uint4*)(bph + kb);
        const uint4* pl = (const uint4*)(bpl + kb);
        bhv0 = ph[0]; bhv1 = ph[1];
        blv0 = pl[0]; blv1 = pl[1];
    };

    char* const cAh = (char*)Ah;
    char* const cAl = (char*)Al;
    char* const cBh = (char*)Bh;
    char* const cBl = (char*)Bl;
    const int wb0 = sr*64 + sk*2;        // base byte of this thread's 32B slot

    stage_load(0);
    for (int kb = 0; kb < IN_DIM; kb += 32) {
        __syncthreads();   // previous iteration's ds_reads complete
        uint hp[8], lp[8];
        #pragma unroll
        for (int jj=0;jj<8;jj++) {
            float v0 = av[2*jj], v1 = av[2*jj+1];
            ushort h0 = f2bf(v0), h1 = f2bf(v1);
            ushort l0 = f2bf(v0 - bf2f(h0)), l1 = f2bf(v1 - bf2f(h1));
            hp[jj] = (uint)h0 | ((uint)h1 << 16);
            lp[jj] = (uint)l0 | ((uint)l1 << 16);
        }
        *(uint4*)(cAh + swz1(sr, wb0))      = *(uint4*)&hp[0];
        *(uint4*)(cAh + swz1(sr, wb0+16))   = *(uint4*)&hp[4];
        *(uint4*)(cAl + swz1(sr, wb0))      = *(uint4*)&lp[0];
        *(uint4*)(cAl + swz1(sr, wb0+16))   = *(uint4*)&lp[4];
        *(uint4*)(cBh + swz1(sr, wb0))      = bhv0;
        *(uint4*)(cBh + swz1(sr, wb0+16))   = bhv1;
        *(uint4*)(cBl + swz1(sr, wb0))      = blv0;
        *(uint4*)(cBl + swz1(sr, wb0+16))   = blv1;
        __syncthreads();
        if (kb + 32 < IN_DIM) stage_load(kb + 32);   // overlap with MFMAs below

        bf16x8 afh[4], afl[4], bfh[4], bfl[4];
        #pragma unroll
        for (int i=0;i<4;i++) {
            const int r = wm*64 + i*16 + fr;
            afh[i] = *(const bf16x8*)(cAh + swz1(r, r*64 + kg*16));
            afl[i] = *(const bf16x8*)(cAl + swz1(r, r*64 + kg*16));
        }
        #pragma unroll
        for (int j=0;j<4;j++) {
            const int c = wn*64 + j*16 + fr;
            bfh[j] = *(const bf16x8*)(cBh + swz1(c, c*64 + kg*16));
            bfl[j] = *(const bf16x8*)(cBl + swz1(c, c*64 + kg*16));
        }
        #pragma unroll
        for (int i=0;i<4;i++)
            #pragma unroll
            for (int j=0;j<4;j++) {
                acc[i][j] = __builtin_amdgcn_mfma_f32_16x16x32_bf16(afh[i], bfh[j], acc[i][j], 0, 0, 0);
                acc[i][j] = __builtin_amdgcn_mfma_f32_16x16x32_bf16(afh[i], bfl[j], acc[i][j], 0, 0, 0);
                acc[i][j] = __builtin_amdgcn_mfma_f32_16x16x32_bf16(afl[i], bfh[j], acc[i][j], 0, 0, 0);
            }
    }

    // epilogue: C/D map col=lane&15, row=(lane>>4)*4+reg  [m89/m91]
    const bool is_root = (nb >= 2);
    if (is_root) {
        const int cb = n0 - 256;
        #pragma unroll
        for (int j=0;j<4;j++) {
            const int col  = cb + wn*64 + j*16 + fr;
            const float bias = b1[col];
            #pragma unroll
            for (int i=0;i<4;i++) {
                const int rbase = m0 + wm*64 + i*16 + kg*4;
                #pragma unroll
                for (int r=0;r<4;r++) {
                    const int row = rbase + r;
                    if (row < N_NODES) h[(size_t)row*HID + col] = acc[i][j][r] + bias;
                }
            }
        }
    } else {
        #pragma unroll
        for (int j=0;j<4;j++) {
            const int col = n0 + wn*64 + j*16 + fr;
            #pragma unroll
            for (int i=0;i<4;i++) {
                const int rbase = m0 + wm*64 + i*16 + kg*4;
                #pragma unroll
                for (int r=0;r<4;r++) {
                    const int row = rbase + r;
                    if (row < N_NODES) xtb[(size_t)row*HID + col] = f2bf(acc[i][j][r]);
                }
            }
        }
    }
}

// ---------------------------------------------------------------------------
// K3: gather1 — one wave per dst node, TWO edges per iteration:
// lanes 0-31 process edge j, lanes 32-63 edge j+1 (16B bf16 loads), halves
// combined via shfl_xor(32). Epilogue fuses root add + dropout + relu and
// writes activated h as bf16 (hb) for the MFMA gemm2.
// ---------------------------------------------------------------------------
__global__ __launch_bounds__(256) void gather1(const int* __restrict__ rowptr,
                                               const int* __restrict__ esrc, const float* __restrict__ a1,
                                               const ushort* __restrict__ xtb,
                                               const float* __restrict__ h,
                                               const float* __restrict__ drop1,
                                               ushort* __restrict__ hb) {
    const int node = blockIdx.x*4 + (threadIdx.x >> 6);
    const int lane = threadIdx.x & 63;
    if (node >= N_NODES) return;
    const int half = lane >> 5, li = lane & 31;
    const int colbase = li*8;
    const int beg = rowptr[node], end = rowptr[node+1];

    float acc[8];
    #pragma unroll
    for (int q=0;q<8;q++) acc[q] = 0.f;

    for (int j = beg; j < end; j += 2) {
        const int jj = j + half;
        int s; float a;
        if (jj < end) { s = esrc[jj]; a = a1[jj]; }
        else          { s = esrc[j];  a = 0.f;    }
        const uint4 v = *(const uint4*)(xtb + (size_t)s*HID + colbase);
        const uint* vw = (const uint*)&v;
        #pragma unroll
        for (int q=0;q<4;q++) {
            acc[2*q]   = fmaf(a, bf2f((ushort)(vw[q] & 0xffffu)), acc[2*q]);
            acc[2*q+1] = fmaf(a, bf2f((ushort)(vw[q] >> 16)),     acc[2*q+1]);
        }
    }
    #pragma unroll
    for (int q=0;q<8;q++) acc[q] += __shfl_xor(acc[q], 32, 64);

    if (half == 0) {
        const float* hp = h + (size_t)node*HID + colbase;
        const float* dp = drop1 + (size_t)node*HID + colbase;
        float hv[8], dv[8];
        *(float4*)&hv[0] = *(const float4*)hp;     *(float4*)&hv[4] = *(const float4*)(hp+4);
        *(float4*)&dv[0] = *(const float4*)dp;     *(float4*)&dv[4] = *(const float4*)(dp+4);
        uint o[4];
        #pragma unroll
        for (int q=0;q<4;q++) {
            float m0 = (dv[2*q]   >= P_DROP) ? INV_KEEP : 0.f;
            float m1 = (dv[2*q+1] >= P_DROP) ? INV_KEEP : 0.f;
            float f0 = fmaxf((hv[2*q]   + acc[2*q])   * m0, 0.f);
            float f1 = fmaxf((hv[2*q+1] + acc[2*q+1]) * m1, 0.f);
            o[q] = (uint)f2bf(f0) | ((uint)f2bf(f1) << 16);
        }
        *(uint4*)(hb + (size_t)node*HID + colbase) = *(uint4*)o;
    }
}

// ---------------------------------------------------------------------------
// K4: gemm2 MFMA: [128 rows x 32 cols] = hb[128 x 256] @ WPT^T.
// acc col frag 0 -> ht2 (W2_msg), frag 1 -> root2 (W2_root + b2).
// FIX (r4 bug): staging ops handle 8 ushorts (one uint4) each, not 16.
// ---------------------------------------------------------------------------
__global__ __launch_bounds__(256) void gemm2_mfma(const ushort* __restrict__ hb,
                                                  const ushort* __restrict__ WPT,
                                                  const float* __restrict__ b2,
                                                  float* __restrict__ ht2, float* __restrict__ root2) {
    __shared__ __align__(16) ushort As[128*256];   // 64KB, 512B rows, swizzled
    __shared__ __align__(16) ushort Bs[32*256];    // 16KB

    const int t = threadIdx.x;
    const int m0 = blockIdx.x * 128;
    char* const cAs = (char*)As;
    char* const cBs = (char*)Bs;

    #pragma unroll
    for (int i = 0; i < 4; ++i) {                  // stage B: 8192 elems / 8 per uint4
        const int idx = (i*256 + t) * 8;
        const int row = idx >> 8, col = idx & 255;
        const uint4 v = *(const uint4*)(WPT + row*256 + col);
        *(uint4*)(cBs + swz2(row, row*512 + col*2)) = v;
    }
    #pragma unroll
    for (int i = 0; i < 16; ++i) {                 // stage A: 32768 elems / 8 per uint4
        const int idx = (i*256 + t) * 8;
        const int row = idx >> 8, col = idx & 255;
        const int gr = m0 + row;
        uint4 v = make_uint4(0u,0u,0u,0u);
        if (gr < N_NODES) v = *(const uint4*)(hb + (size_t)gr*HID + col);
        *(uint4*)(cAs + swz2(row, row*512 + col*2)) = v;
    }
    __syncthreads();

    const int w = t >> 6, lane = t & 63;
    const int fr = lane & 15, kg = lane >> 4;

    f32x4 acc[2][2];
    #pragma unroll
    for (int i=0;i<2;i++)
        #pragma unroll
        for (int j=0;j<2;j++) acc[i][j] = (f32x4){0.f,0.f,0.f,0.f};

    #pragma unroll
    for (int ks = 0; ks < 8; ++ks) {
        bf16x8 af[2], bfv[2];
        #pragma unroll
        for (int i=0;i<2;i++) {
            const int r = w*32 + i*16 + fr;
            af[i] = *(const bf16x8*)(cAs + swz2(r, r*512 + ks*64 + kg*16));
        }
        #pragma unroll
        for (int j=0;j<2;j++) {
            const int c = j*16 + fr;
            bfv[j] = *(const bf16x8*)(cBs + swz2(c, c*512 + ks*64 + kg*16));
        }
        #pragma unroll
        for (int i=0;i<2;i++)
            #pragma unroll
            for (int j=0;j<2;j++)
                acc[i][j] = __builtin_amdgcn_mfma_f32_16x16x32_bf16(af[i], bfv[j], acc[i][j], 0, 0, 0);
    }

    if (fr < OUT_DIM) {
        const float bias = b2[fr];
        #pragma unroll
        for (int i=0;i<2;i++) {
            const int rbase = m0 + w*32 + i*16 + kg*4;
            #pragma unroll
            for (int r=0;r<4;r++) {
                const int row = rbase + r;
                if (row < N_NODES) {
                    ht2  [(size_t)row*OUT_DIM + fr] = acc[i][0][r];
                    root2[(size_t)row*OUT_DIM + fr] = acc[i][1][r] + bias;
                }
            }
        }
    }
}

// ---------------------------------------------------------------------------
// K5: gather2 — one thread per node, 9-float accumulator; fused relu-dropout.
// ---------------------------------------------------------------------------
__global__ __launch_bounds__(256) void gather2(const int* __restrict__ rowptr,
                                               const int* __restrict__ esrc, const float* __restrict__ a2,
                                               const float* __restrict__ ht2,
                                               const float* __restrict__ root2,
                                               const float* __restrict__ drop2,
                                               float* __restrict__ outp) {
    const int n = blockIdx.x*256 + threadIdx.x;
    if (n >= N_NODES) return;
    float acc[OUT_DIM];
    #pragma unroll
    for (int k=0;k<OUT_DIM;k++) acc[k] = root2[(size_t)n*OUT_DIM + k];
    const int beg = rowptr[n], end = rowptr[n+1];
    for (int j = beg; j < end; ++j) {
        const int s = esrc[j];
        const float a = a2[j];
        const float* sp = ht2 + (size_t)s*OUT_DIM;
        #pragma unroll
        for (int k=0;k<OUT_DIM;k++) acc[k] = fmaf(a, sp[k], acc[k]);
    }
    #pragma unroll
    for (int k=0;k<OUT_DIM;k++) {
        const float m = (drop2[(size_t)n*OUT_DIM + k] >= P_DROP) ? INV_KEEP : 0.f;
        const float v = acc[k]*m;
        outp[(size_t)n*OUT_DIM + k] = v > 0.f ? v : 0.f;
    }
}

// ---------------------------------------------------------------------------
extern "C" void kernel_launch(void* const* d_in, const int* in_sizes, int n_in,
                              void* d_out, int out_size, void* d_ws, size_t ws_size,
                              hipStream_t stream) {
    const float* x      = (const float*)d_in[0];
    const int*   eidx   = (const int*)d_in[1];
    const int*   etype  = (const int*)d_in[2];
    const int*   edist  = (const int*)d_in[3];
    const float* drop1  = (const float*)d_in[4];
    const float* drop2  = (const float*)d_in[5];
    const float* W1m    = (const float*)d_in[6];
    const float* W1r    = (const float*)d_in[7];
    const float* b1     = (const float*)d_in[8];
    const float* te1    = (const float*)d_in[9];
    const float* de1    = (const float*)d_in[10];
    const float* g1w    = (const float*)d_in[11];
    const float* g1b    = (const float*)d_in[12];
    const float* W2m    = (const float*)d_in[13];
    const float* W2r    = (const float*)d_in[14];
    const float* b2     = (const float*)d_in[15];
    const float* te2    = (const float*)d_in[16];
    const float* de2    = (const float*)d_in[17];
    const float* g2w    = (const float*)d_in[18];
    const float* g2b    = (const float*)d_in[19];
    float* out = (float*)d_out;

    const int* src = eidx;
    const int* dst = eidx + N_EDGESC;

    // workspace layout (~118MB)
    float* ws    = (float*)d_ws;
    float* h     = ws;                                   // 12,800,000 f
    float* ht2   = h     + (size_t)N_NODES*HID;          // 450,000 f
    float* root2 = ht2   + (size_t)N_NODES*OUT_DIM;      // 450,000 f
    float* tbl   = root2 + (size_t)N_NODES*OUT_DIM;      // 384 f
    float* a1    = tbl   + 384;                          // 800,000 f
    float* a2    = a1    + N_EDGESC;                     // 800,000 f
    int*   esrc  = (int*)(a2 + N_EDGESC);                // 800,000 i
    int*   deg   = esrc  + N_EDGESC;                     // 50,000 i
    int*   rowptr= deg   + N_NODES;                      // 50,001 -> pad 50,004
    int*   cursor= rowptr+ 50004;                        // 50,000 -> pad 50,004
    int*   bsum  = cursor+ 50004;                        // 196 -> pad 256
    int*   boff  = bsum  + 256;                          // 196 -> pad 256
    ushort* xtb  = (ushort*)(boff + 256);                // 12,800,000 u16
    ushort* hb   = xtb + (size_t)N_NODES*HID;            // 12,800,000 u16
    ushort* BTh  = hb  + (size_t)N_NODES*HID;            // 393,216 u16
    ushort* BTl  = BTh + (size_t)512*IN_DIM;             // 393,216 u16
    ushort* WPT  = BTl + (size_t)512*IN_DIM;             // 8,192 u16

    gate_tables<<<1, 512, 0, stream>>>(te1, de1, g1w, te2, de2, g2w, tbl);
    bt_prep<<<(512*IN_DIM+255)/256, 256, 0, stream>>>(W1m, W1r, BTh, BTl);
    w2_pack<<<32, 256, 0, stream>>>(W2m, W2r, WPT);
    zero_deg<<<(N_NODES+255)/256, 256, 0, stream>>>(deg);
    hist<<<(N_EDGESC+255)/256, 256, 0, stream>>>(dst, deg);
    scan_p1<<<196, 256, 0, stream>>>(deg, bsum);
    scan_p2<<<1, 256, 0, stream>>>(bsum, boff);
    scan_p3<<<196, 256, 0, stream>>>(deg, boff, rowptr, cursor);
    fill_csr<<<(N_EDGESC+255)/256, 256, 0, stream>>>(src, dst, etype, edist, tbl, g1b, g2b,
                                                     cursor, esrc, a1, a2);
    gemm1_mfma<<<dim3(4, (N_NODES+127)/128), 256, 0, stream>>>(x, BTh, BTl, b1, xtb, h);
    gather1<<<(N_NODES+3)/4, 256, 0, stream>>>(rowptr, esrc, a1, xtb, h, drop1, hb);
    gemm2_mfma<<<(N_NODES+127)/128, 256, 0, stream>>>(hb, WPT, b2, ht2, root2);
    gather2<<<(N_NODES+255)/256, 256, 0, stream>>>(rowptr, esrc, a2, ht2, root2, drop2, out);
}